// Round 3
// baseline (244.558 us; speedup 1.0000x reference)
//
#include <hip/hip_runtime.h>

// MultiHeadAttention: S=2048, B=2, EMB=512, H=8, D=64 -> 16 independent (b,h)
// groups of [2048 x 64] attention, plus per-head 64x64 QKV projections and a
// 512x512 output FC. All matmuls in bf16 MFMA (16x16x32), fp32 accumulate.
//
// R3: latency-bound fix. flash runs TWO independent key-chains per wave
// (ILP x2, merged at epilogue). fc and proj load MFMA fragments directly
// from global (row-major along k) -- no LDS staging, no barriers in fc.
//
// ws layout (u16/bf16): Qb[32768*64] | Kb[32768*64] | Vt[16][64][2048] | Att[32768*64]

typedef __attribute__((ext_vector_type(8))) __bf16 bf16x8;
typedef __attribute__((ext_vector_type(4))) float f32x4;
typedef __attribute__((ext_vector_type(4))) unsigned short u16x4;
typedef __attribute__((ext_vector_type(4))) unsigned int u32x4;
typedef unsigned short u16;
typedef unsigned int u32;

static __device__ __forceinline__ u16 f2bf(float x) {
    u32 u = __float_as_uint(x);
    u += 0x7fff + ((u >> 16) & 1);   // RNE; inputs are normal floats (no NaN)
    return (u16)(u >> 16);
}
static __device__ __forceinline__ u32 pack2bf(float lo, float hi) {
    u32 a = __float_as_uint(lo), b = __float_as_uint(hi);
    a += 0x7fff + ((a >> 16) & 1);
    b += 0x7fff + ((b >> 16) & 1);
    return (a >> 16) | (b & 0xffff0000u);
}
// pack 8 consecutive fp32 (two float4) into a bf16x8 fragment
static __device__ __forceinline__ bf16x8 pack8(float4 a, float4 b) {
    u32x4 r = { pack2bf(a.x, a.y), pack2bf(a.z, a.w),
                pack2bf(b.x, b.y), pack2bf(b.z, b.w) };
    union { u32x4 u; bf16x8 h; } cvt; cvt.u = r; return cvt.h;
}

// ---------------------------------------------------------------------------
// Kernel 1: QKV projection.  Y = (X @ W^T) * scale, X flat [32768 x 64].
// mode 0 -> Qb (scale = 1/sqrt(64)*log2e), 1 -> Kb, 2 -> Vt (transposed
// within group: Vt[(g*64+d)*2048+s]).  Fragments packed in-register from
// global fp32; LDS used only to stage outputs for coalesced stores.
// ---------------------------------------------------------------------------
__global__ __launch_bounds__(256) void proj_kernel(
    const float* __restrict__ q, const float* __restrict__ k, const float* __restrict__ v,
    const float* __restrict__ Wq, const float* __restrict__ Wk, const float* __restrict__ Wv,
    u16* __restrict__ Qb, u16* __restrict__ Kb, u16* __restrict__ Vt)
{
    const int mode = blockIdx.z;
    const float* A = (mode == 0) ? q : (mode == 1) ? k : v;
    const float* W = (mode == 0) ? Wq : (mode == 1) ? Wk : Wv;
    const float osc = (mode == 0) ? 0.18033688011112042f : 1.0f; // 0.125*log2(e)

    __shared__ alignas(16) u16 Ssh[128 * 136];   // output stage (mode2 needs 64x136)

    const int t = threadIdx.x;
    const int m0 = blockIdx.x * 128;
    const int w = t >> 6, l = t & 63;
    const int r16 = l & 15, q4 = l >> 4;

    // fragments straight from global (fp32 -> bf16 pack in-register)
    bf16x8 af[2][2], wf[4][2];
    #pragma unroll
    for (int mc = 0; mc < 2; ++mc)
        #pragma unroll
        for (int kk = 0; kk < 2; ++kk) {
            const float* p = A + (size_t)(m0 + w * 32 + mc * 16 + r16) * 64 + kk * 32 + q4 * 8;
            af[mc][kk] = pack8(*(const float4*)p, *(const float4*)(p + 4));
        }
    #pragma unroll
    for (int nc = 0; nc < 4; ++nc)
        #pragma unroll
        for (int kk = 0; kk < 2; ++kk) {
            const float* p = W + (size_t)(nc * 16 + r16) * 64 + kk * 32 + q4 * 8;
            wf[nc][kk] = pack8(*(const float4*)p, *(const float4*)(p + 4));
        }

    f32x4 acc[2][4];
    const f32x4 zero = {0.f, 0.f, 0.f, 0.f};
    #pragma unroll
    for (int mc = 0; mc < 2; ++mc)
        #pragma unroll
        for (int nc = 0; nc < 4; ++nc) {
            acc[mc][nc] = zero;
            acc[mc][nc] = __builtin_amdgcn_mfma_f32_16x16x32_bf16(af[mc][0], wf[nc][0], acc[mc][nc], 0, 0, 0);
            acc[mc][nc] = __builtin_amdgcn_mfma_f32_16x16x32_bf16(af[mc][1], wf[nc][1], acc[mc][nc], 0, 0, 0);
        }

    // C/D layout: col(n) = lane&15, row(m) = quad*4 + reg
    if (mode < 2) {
        #pragma unroll
        for (int mc = 0; mc < 2; ++mc)
            #pragma unroll
            for (int nc = 0; nc < 4; ++nc)
                #pragma unroll
                for (int r = 0; r < 4; ++r)
                    Ssh[(w * 32 + mc * 16 + q4 * 4 + r) * 72 + nc * 16 + r16] = f2bf(acc[mc][nc][r] * osc);
        __syncthreads();
        u16* Out = ((mode == 0) ? Qb : Kb) + (size_t)m0 * 64;
        int row = t >> 1, cbase = (t & 1) * 32;
        #pragma unroll
        for (int i = 0; i < 4; ++i)
            *(u32x4*)(Out + row * 64 + cbase + i * 8) = *(const u32x4*)(Ssh + row * 72 + cbase + i * 8);
    } else {
        // transpose: Ssh[d][s-local], d = nc*16+r16, s-local = w*32+mc*16+q4*4+r
        #pragma unroll
        for (int mc = 0; mc < 2; ++mc)
            #pragma unroll
            for (int nc = 0; nc < 4; ++nc)
                #pragma unroll
                for (int r = 0; r < 4; ++r)
                    Ssh[(nc * 16 + r16) * 136 + w * 32 + mc * 16 + q4 * 4 + r] = f2bf(acc[mc][nc][r]);
        __syncthreads();
        const int g = m0 >> 11, s0 = m0 & 2047;
        int d = t >> 2, sb = (t & 3) * 32;
        u16* Out = Vt + ((size_t)(g * 64 + d)) * 2048 + s0;
        #pragma unroll
        for (int i = 0; i < 4; ++i)
            *(u32x4*)(Out + sb + i * 8) = *(const u32x4*)(Ssh + d * 136 + sb + i * 8);
    }
}

// ---------------------------------------------------------------------------
// Kernel 2: flash attention, S^T orientation, two independent key-chains per
// wave (chain c covers keys [c*1024, c*1024+1024), 32 iters of 32 keys).
// Q pre-scaled by 1/sqrt(d)*log2e -> softmax in exp2 domain.  No block
// barriers; per-wave LDS only for the P C-layout -> B-frag transform.
// ---------------------------------------------------------------------------
__global__ __launch_bounds__(256, 2) void flash_kernel(
    const u16* __restrict__ Qb, const u16* __restrict__ Kb,
    const u16* __restrict__ Vt, u16* __restrict__ Att)
{
    const int g = blockIdx.y;    // 0..15
    const int qt = blockIdx.x;   // 0..31
    const int t = threadIdx.x, w = t >> 6, l = t & 63;
    const int r16 = l & 15, q4 = l >> 4;

    __shared__ alignas(16) u16 Psh[4][2][16 * 40];   // [wave][chain][q=16][key=32 pad 40]

    const u16* Kg = Kb + ((size_t)g) * 2048 * 64;
    const u16* Vg = Vt + ((size_t)g) * 64 * 2048;

    // Q B-frag: B[n=q][k=d], lane n=r16, k=q4*8+j (+32)
    bf16x8 qb[2];
    {
        const u16* qp = Qb + ((size_t)(g * 2048 + qt * 64 + w * 16 + r16)) * 64 + q4 * 8;
        qb[0] = *(const bf16x8*)qp;
        qb[1] = *(const bf16x8*)(qp + 32);
    }

    f32x4 o[2][4];
    const f32x4 zero = {0.f, 0.f, 0.f, 0.f};
    #pragma unroll
    for (int c = 0; c < 2; ++c)
        #pragma unroll
        for (int dc = 0; dc < 4; ++dc) o[c][dc] = zero;
    float m2[2] = { -INFINITY, -INFINITY }, ls[2] = { 0.f, 0.f };

    // preload K tile 0 for both chains: A[m=key][k=d], lane m=r16
    bf16x8 ka[2][2][2];
    #pragma unroll
    for (int c = 0; c < 2; ++c)
        #pragma unroll
        for (int kc = 0; kc < 2; ++kc) {
            const u16* kp = Kg + ((size_t)(c * 1024 + kc * 16 + r16)) * 64 + q4 * 8;
            ka[c][kc][0] = *(const bf16x8*)kp;
            ka[c][kc][1] = *(const bf16x8*)(kp + 32);
        }

    u16* pw[2] = { &Psh[w][0][r16 * 40], &Psh[w][1][r16 * 40] };

    for (int it = 0; it < 32; ++it) {
        // V^T A-frags for current tile, both chains: A[m=d][k=key]
        bf16x8 va[2][4];
        #pragma unroll
        for (int c = 0; c < 2; ++c)
            #pragma unroll
            for (int dc = 0; dc < 4; ++dc)
                va[c][dc] = *(const bf16x8*)(Vg + ((size_t)(dc * 16 + r16)) * 2048
                                             + c * 1024 + it * 32 + q4 * 8);

        // S^T = K.Q^T : lane holds q-col r16, keys kc*16 + q4*4 + r
        f32x4 s[2][2];
        #pragma unroll
        for (int c = 0; c < 2; ++c)
            #pragma unroll
            for (int kc = 0; kc < 2; ++kc) {
                s[c][kc] = zero;
                s[c][kc] = __builtin_amdgcn_mfma_f32_16x16x32_bf16(ka[c][kc][0], qb[0], s[c][kc], 0, 0, 0);
                s[c][kc] = __builtin_amdgcn_mfma_f32_16x16x32_bf16(ka[c][kc][1], qb[1], s[c][kc], 0, 0, 0);
            }

        // prefetch next K tile, both chains (wraps harmlessly on last iter)
        const int itn = (it + 1) & 31;
        bf16x8 kn[2][2][2];
        #pragma unroll
        for (int c = 0; c < 2; ++c)
            #pragma unroll
            for (int kc = 0; kc < 2; ++kc) {
                const u16* kp = Kg + ((size_t)(c * 1024 + itn * 32 + kc * 16 + r16)) * 64 + q4 * 8;
                kn[c][kc][0] = *(const bf16x8*)kp;
                kn[c][kc][1] = *(const bf16x8*)(kp + 32);
            }

        // online softmax per chain (per-lane scalar state, q = r16)
        float p[2][2][4];
        #pragma unroll
        for (int c = 0; c < 2; ++c) {
            float mx = fmaxf(fmaxf(fmaxf(s[c][0][0], s[c][0][1]), fmaxf(s[c][0][2], s[c][0][3])),
                             fmaxf(fmaxf(s[c][1][0], s[c][1][1]), fmaxf(s[c][1][2], s[c][1][3])));
            mx = fmaxf(mx, __shfl_xor(mx, 16));
            mx = fmaxf(mx, __shfl_xor(mx, 32));
            float mn = fmaxf(m2[c], mx);
            float alpha = exp2f(m2[c] - mn);
            m2[c] = mn;
            float psum = 0.f;
            #pragma unroll
            for (int kc = 0; kc < 2; ++kc)
                #pragma unroll
                for (int r = 0; r < 4; ++r) {
                    p[c][kc][r] = exp2f(s[c][kc][r] - mn);
                    psum += p[c][kc][r];
                }
            ls[c] = ls[c] * alpha + psum;
            #pragma unroll
            for (int dc = 0; dc < 4; ++dc)
                #pragma unroll
                for (int r = 0; r < 4; ++r) o[c][dc][r] *= alpha;
        }

        // P^T (C-layout) -> per-wave LDS -> B-frag, then PV, per chain
        #pragma unroll
        for (int c = 0; c < 2; ++c) {
            #pragma unroll
            for (int kc = 0; kc < 2; ++kc) {
                uint2 dd = { pack2bf(p[c][kc][0], p[c][kc][1]),
                             pack2bf(p[c][kc][2], p[c][kc][3]) };
                *(uint2*)(pw[c] + kc * 16 + q4 * 4) = dd;
            }
        }
        #pragma unroll
        for (int c = 0; c < 2; ++c) {
            bf16x8 pb = *(const bf16x8*)(pw[c] + q4 * 8);  // B[n=q=r16][k=key]
            #pragma unroll
            for (int dc = 0; dc < 4; ++dc)
                o[c][dc] = __builtin_amdgcn_mfma_f32_16x16x32_bf16(va[c][dc], pb, o[c][dc], 0, 0, 0);
        }

        #pragma unroll
        for (int c = 0; c < 2; ++c)
            #pragma unroll
            for (int kc = 0; kc < 2; ++kc) {
                ka[c][kc][0] = kn[c][kc][0];
                ka[c][kc][1] = kn[c][kc][1];
            }
    }

    // merge the two chains, reduce l across lane groups, normalize, store
    float mM = fmaxf(m2[0], m2[1]);
    float w0 = exp2f(m2[0] - mM), w1 = exp2f(m2[1] - mM);
    float lM = ls[0] * w0 + ls[1] * w1;
    lM += __shfl_xor(lM, 16);
    lM += __shfl_xor(lM, 32);
    float inv = 1.0f / lM;
    const int qq = qt * 64 + w * 16 + r16;
    u16* orow = Att + ((size_t)(g * 2048 + qq)) * 64;
    #pragma unroll
    for (int dc = 0; dc < 4; ++dc) {
        u16x4 bb = { f2bf((o[0][dc][0] * w0 + o[1][dc][0] * w1) * inv),
                     f2bf((o[0][dc][1] * w0 + o[1][dc][1] * w1) * inv),
                     f2bf((o[0][dc][2] * w0 + o[1][dc][2] * w1) * inv),
                     f2bf((o[0][dc][3] * w0 + o[1][dc][3] * w1) * inv) };
        *(u16x4*)(orow + dc * 16 + q4 * 4) = bb;
    }
}

// ---------------------------------------------------------------------------
// Kernel 3: out = Att @ Wfc^T + bfc.  M=4096, N=512, K=512.
// Zero LDS, zero barriers: A (bf16) and W (fp32, packed in-register) frags
// load directly from global.  BM=64 (16 rows/wave), BN=64; grid (64,8).
// ---------------------------------------------------------------------------
__global__ __launch_bounds__(256) void fc_kernel(
    const u16* __restrict__ Att, const float* __restrict__ Wfc,
    const float* __restrict__ bfc, float* __restrict__ out)
{
    const int t = threadIdx.x, w = t >> 6, l = t & 63;
    const int r16 = l & 15, q4 = l >> 4;
    const int m0 = blockIdx.x * 64, n0 = blockIdx.y * 64;

    const u16* arow = Att + (size_t)(m0 + w * 16 + r16) * 512 + q4 * 8;

    f32x4 acc[4];
    const f32x4 zero = {0.f, 0.f, 0.f, 0.f};
    #pragma unroll
    for (int nc = 0; nc < 4; ++nc) acc[nc] = zero;

    #pragma unroll 2
    for (int k0 = 0; k0 < 512; k0 += 64) {
        bf16x8 af[2], wf[4][2];
        #pragma unroll
        for (int kk = 0; kk < 2; ++kk)
            af[kk] = *(const bf16x8*)(arow + k0 + kk * 32);
        #pragma unroll
        for (int nc = 0; nc < 4; ++nc)
            #pragma unroll
            for (int kk = 0; kk < 2; ++kk) {
                const float* p = Wfc + (size_t)(n0 + nc * 16 + r16) * 512 + k0 + kk * 32 + q4 * 8;
                wf[nc][kk] = pack8(*(const float4*)p, *(const float4*)(p + 4));
            }
        #pragma unroll
        for (int nc = 0; nc < 4; ++nc) {
            acc[nc] = __builtin_amdgcn_mfma_f32_16x16x32_bf16(af[0], wf[nc][0], acc[nc], 0, 0, 0);
            acc[nc] = __builtin_amdgcn_mfma_f32_16x16x32_bf16(af[1], wf[nc][1], acc[nc], 0, 0, 0);
        }
    }

    #pragma unroll
    for (int nc = 0; nc < 4; ++nc) {
        float bb = bfc[n0 + nc * 16 + r16];
        #pragma unroll
        for (int r = 0; r < 4; ++r) {
            int row = m0 + w * 16 + q4 * 4 + r;
            out[(size_t)row * 512 + n0 + nc * 16 + r16] = acc[nc][r] + bb;
        }
    }
}

extern "C" void kernel_launch(void* const* d_in, const int* in_sizes, int n_in,
                              void* d_out, int out_size, void* d_ws, size_t ws_size,
                              hipStream_t stream) {
    (void)in_sizes; (void)n_in; (void)out_size; (void)ws_size;
    const float* q   = (const float*)d_in[0];
    const float* k   = (const float*)d_in[1];
    const float* v   = (const float*)d_in[2];
    const float* Wq  = (const float*)d_in[3];
    const float* Wk  = (const float*)d_in[4];
    const float* Wv  = (const float*)d_in[5];
    const float* Wfc = (const float*)d_in[6];
    const float* bfc = (const float*)d_in[7];
    float* out = (float*)d_out;

    u16* Qb = (u16*)d_ws;                 // 32768*64 bf16 (pre-scaled by sc*log2e)
    u16* Kb = Qb + 2097152;
    u16* Vt = Kb + 2097152;               // [16][64][2048]
    u16* At = Vt + 2097152;               // 32768*64 bf16

    proj_kernel<<<dim3(256, 1, 3), 256, 0, stream>>>(q, k, v, Wq, Wk, Wv, Qb, Kb, Vt);
    flash_kernel<<<dim3(32, 16), 256, 0, stream>>>(Qb, Kb, Vt, At);
    fc_kernel<<<dim3(64, 8), 256, 0, stream>>>(At, Wfc, bfc, out);
}